// Round 6
// baseline (522.790 us; speedup 1.0000x reference)
//
#include <hip/hip_runtime.h>
#include <hip/hip_bf16.h>
#include <math.h>

// Problem constants (B=2,S=2048,D=1024,E=8,F=4096, capacity_factor=2.0)
#define T_TOK 4096
#define DDIM 1024
#define EXP 8
#define FDIM 4096
#define CAP 1024   // int(2.0 * 4096 / 8)

typedef __attribute__((ext_vector_type(8))) short short8;
typedef __attribute__((ext_vector_type(4))) float float4v;
typedef unsigned int u32;
typedef unsigned long long u64;

// ---- workspace layout (bytes) ----
#define O_EIDX   0            // int[4096]
#define O_GATE   (16<<10)     // float[4096]
#define O_COUNTS (32<<10)     // int[8]
#define O_SUMP   ((32<<10)+64)  // float[8]
#define O_ZSUM   ((32<<10)+128) // float[1]
#define O_TLIST  (40<<10)     // int[8*1024]
#define O_GSLOT  (72<<10)     // float[8*1024]
#define O_XB     (1<<20)      // bf16[8*1024*1024]   16 MiB
#define O_WT     (17<<20)     // bf16[8*4096*1024]   64 MiB (reused W1t then W2t)
#define O_H      (81<<20)     // bf16[8*1024*4096]   64 MiB
#define O_PT     (145<<20)    // fp32[2][8*1024][1024] 64 MiB split-K partials

__device__ __forceinline__ unsigned short f2bf(float f) {
  __hip_bfloat16 b = __float2bfloat16(f);
  return *reinterpret_cast<unsigned short*>(&b);
}
__device__ __forceinline__ float bf2f(unsigned short u) {
  u32 x = ((u32)u) << 16;
  union { u32 u; float f; } c; c.u = x; return c.f;
}

__device__ __forceinline__ void gld16(const void* g, void* l) {
  __builtin_amdgcn_global_load_lds((const __attribute__((address_space(1))) u32*)g,
                                   (__attribute__((address_space(3))) u32*)l, 16, 0, 0);
}

// ---------------- router: logits (fp64 acc), softmax, argmax, loss partials ----------------
__global__ __launch_bounds__(256) void router_kernel(
    const float* __restrict__ x, const float* __restrict__ wg,
    int* __restrict__ eidx, float* __restrict__ gate,
    float* __restrict__ sum_probs, float* __restrict__ zsum)
{
  __shared__ float bp[9];
  const int tid = threadIdx.x;
  if (tid < 9) bp[tid] = 0.0f;
  __syncthreads();
  const int wv = tid >> 6, lane = tid & 63;
  const int t = blockIdx.x * 4 + wv;
  const float* xr = x + (size_t)t * DDIM;
  double acc[8] = {0,0,0,0,0,0,0,0};
#pragma unroll
  for (int j = 0; j < 4; j++) {
    const int d0 = j * 256 + lane * 4;
    const float4 xv = *(const float4*)&xr[d0];
    const float xd[4] = {xv.x, xv.y, xv.z, xv.w};
#pragma unroll
    for (int u = 0; u < 4; u++) {
      const float* wr = wg + (size_t)(d0 + u) * 8;
      const float4 w0 = *(const float4*)wr;
      const float4 w1 = *(const float4*)(wr + 4);
      const double xdd = (double)xd[u];
      acc[0] += xdd * (double)w0.x; acc[1] += xdd * (double)w0.y;
      acc[2] += xdd * (double)w0.z; acc[3] += xdd * (double)w0.w;
      acc[4] += xdd * (double)w1.x; acc[5] += xdd * (double)w1.y;
      acc[6] += xdd * (double)w1.z; acc[7] += xdd * (double)w1.w;
    }
  }
#pragma unroll
  for (int e = 0; e < 8; e++)
#pragma unroll
    for (int off = 32; off; off >>= 1)
      acc[e] += __shfl_xor(acc[e], off);
  if (lane == 0) {
    double m = acc[0]; int am = 0;
#pragma unroll
    for (int e = 1; e < 8; e++) if (acc[e] > m) { m = acc[e]; am = e; }
    float p[8]; float se = 0.f;
#pragma unroll
    for (int e = 0; e < 8; e++) { p[e] = __expf((float)(acc[e] - m)); se += p[e]; }
    const float inv = 1.f / se;
#pragma unroll
    for (int e = 0; e < 8; e++) atomicAdd(&bp[e], p[e] * inv);
    const float z = logf(se) + (float)m;
    atomicAdd(&bp[8], z * z);
    eidx[t] = am;
    gate[t] = p[am] * inv;
  }
  __syncthreads();
  if (tid < 8) atomicAdd(&sum_probs[tid], bp[tid]);
  if (tid == 8) atomicAdd(zsum, bp[8]);
}

// ---------------- scan: per-expert positions (token order) + loss finalize ----------------
__global__ __launch_bounds__(512) void scan_kernel(
    const int* __restrict__ eidx, const float* __restrict__ gate,
    int* __restrict__ tlist, float* __restrict__ gslot, int* __restrict__ counts,
    const float* __restrict__ sump, const float* __restrict__ zsum,
    float* __restrict__ y)
{
  __shared__ int se[T_TOK];
  __shared__ int cshare[8];
  const int tid = threadIdx.x;
  for (int i = tid; i < T_TOK; i += 512) se[i] = eidx[i];
  __syncthreads();
  const int w = tid >> 6, lane = tid & 63;
  int base = 0;
  for (int ch = 0; ch < T_TOK / 64; ch++) {
    const int t = ch * 64 + lane;
    const int e = se[t];
    const u64 m = __ballot(e == w);
    if (e == w) {
      const int p = base + __popcll(m & ((1ull << lane) - 1ull));
      if (p < CAP) {
        tlist[w * CAP + p] = t;
        gslot[w * CAP + p] = gate[t];
      }
    }
    base += __popcll(m);
  }
  if (lane == 0) { counts[w] = base; cshare[w] = base; }  // raw count (aux loss)
  __syncthreads();
  if (tid == 0) {
    float aux = 0.f;
#pragma unroll
    for (int e = 0; e < 8; e++) aux += (float)cshare[e] * sump[e];
    float* outs = y + (size_t)T_TOK * DDIM;
    outs[0] = 8.f * aux / ((float)T_TOK * (float)T_TOK);
    outs[1] = zsum[0] * (1.f / (float)T_TOK);
  }
}

// ---------------- dispatch: gather kept tokens into compact bf16 buffer ----------------
__global__ __launch_bounds__(256) void dispatch_kernel(
    const float* __restrict__ x, const int* __restrict__ tlist,
    const int* __restrict__ counts, unsigned short* __restrict__ xb)
{
  const int wv = threadIdx.x >> 6, lane = threadIdx.x & 63;
  const int s = blockIdx.x * 4 + wv;           // slot id
  const int e = s >> 10, c = s & (CAP - 1);
  int cnt = counts[e]; cnt = cnt < CAP ? cnt : CAP;
  if (c >= cnt) return;
  const int t = tlist[s];
  const float* xr = x + (size_t)t * DDIM;
  unsigned short* orow = xb + (size_t)s * DDIM;
#pragma unroll
  for (int j = 0; j < 4; j++) {
    const int d0 = j * 256 + lane * 4;
    const float4 v = *(const float4*)&xr[d0];
    const u64 pk = (u64)f2bf(v.x) | ((u64)f2bf(v.y) << 16) |
                   ((u64)f2bf(v.z) << 32) | ((u64)f2bf(v.w) << 48);
    *(u64*)&orow[d0] = pk;
  }
}

// ---------------- transpose + fp32->bf16: [R][C] -> [C][R] per matrix ----------------
__global__ __launch_bounds__(256) void transpose_cvt(
    const float* __restrict__ src, unsigned short* __restrict__ dst, int R, int C)
{
  __shared__ float tile[64][65];
  const size_t mb = (size_t)blockIdx.z * (size_t)R * (size_t)C;
  const int r0 = blockIdx.y * 64, c0 = blockIdx.x * 64;
  const int t = threadIdx.x;
  const int lr = t >> 4, lc = (t & 15) * 4;
#pragma unroll
  for (int p = 0; p < 4; p++) {
    const float4 v = *(const float4*)&src[mb + (size_t)(r0 + p * 16 + lr) * C + c0 + lc];
    tile[p * 16 + lr][lc + 0] = v.x; tile[p * 16 + lr][lc + 1] = v.y;
    tile[p * 16 + lr][lc + 2] = v.z; tile[p * 16 + lr][lc + 3] = v.w;
  }
  __syncthreads();
  const int n = t >> 2;            // out row within tile (0..63)
  const int k0 = (t & 3) * 16;
  unsigned short o[16];
#pragma unroll
  for (int j = 0; j < 16; j++) o[j] = f2bf(tile[k0 + j][n]);
  unsigned short* d = &dst[mb + (size_t)(c0 + n) * R + r0 + k0];
  *(short8*)d = *(short8*)&o[0];
  *(short8*)(d + 8) = *(short8*)&o[8];
}

// ======================= GEMM core: 256xBN, BK=64, 4-phase counted-vmcnt schedule =========
// LDS swizzle: chunk c (8 ushorts) of row r holds global k-chunk c ^ (r&7) (conflict-free).
// Staging source offset per lane: ((lane&7) ^ (lane>>3)) * 8; frag chunk: (ks*4+quad)^(l15&7).
// 8 waves (2M x BN/64-wide n each), 512 threads. Per K-tile: 4 phases
// {ds_read quadrant ∥ stage 1 half-tile; barrier; lgkmcnt(0); setprio(1); MFMA; setprio(0);
// barrier}; quadrants (Alo·Blo)(Alo·Bhi)(Ahi·Bhi)(Ahi·Blo); staging spiral A-lo(t+1),
// A-hi(t+1), B-lo(t+2), B-hi(t+2); one counted vmcnt per K-tile, never 0 mid-loop.
// Ledger BN=256: outstanding@p4 = A(t+1)4 + B(t+2)4 = 8 -> vmcnt(4) drains A(t+1).
// Ledger BN=128: outstanding@p4 = A(t+1)4 + B(t+2)2 = 6 -> vmcnt(2) drains A(t+1).
template<int KS, int BN>
__device__ __forceinline__ void gemm256_core(
    const unsigned short* __restrict__ Ab, const unsigned short* __restrict__ Bb,
    unsigned short* As, unsigned short* Bs,
    int k_lo, int NT, float4v (*acc)[BN / 64])
{
  const int NTH = BN / 128;       // n-frags per lo/hi quadrant per wave (2 or 1)
  const int BSZ = BN * 64;        // B buffer elems per K-tile
  const int tid = threadIdx.x;
  const int w = tid >> 6, lane = tid & 63;
  const int lrow = lane >> 3;                 // 0..7
  const int lk_sw = ((lane & 7) ^ lrow) * 8;  // swizzled source k-offset (elements)
  const int wr = w >> 2, wc = w & 3;
  const int l15 = lane & 15, quad = lane >> 4;
  const int xq = l15 & 7;
  const int co0 = (quad ^ xq) * 8;            // frag chunk offset, ks=0
  const int co1 = ((4 + quad) ^ xq) * 8;      // frag chunk offset, ks=1
  const int arow = (wr * 128 + l15) * 64;     // A frag row base (elements)
  const int brow = (wc * (BN / 4) + l15) * 64;// B frag row base (elements)

#define STG_A(buf_, half_, tk_) do { \
    const int rb_ = (half_) * 128 + w * 16; \
    const size_t ko_ = (size_t)(k_lo + ((tk_) << 6) + lk_sw); \
    gld16(Ab + (size_t)(rb_ + lrow) * KS + ko_,     As + (buf_) * 16384 + rb_ * 64); \
    gld16(Ab + (size_t)(rb_ + 8 + lrow) * KS + ko_, As + (buf_) * 16384 + (rb_ + 8) * 64); \
  } while (0)
#define STG_B(buf_, half_, tk_) do { \
    const size_t ko_ = (size_t)(k_lo + ((tk_) << 6) + lk_sw); \
    if (BN == 256) { \
      const int rb_ = (half_) * 128 + w * 16; \
      gld16(Bb + (size_t)(rb_ + lrow) * KS + ko_,     Bs + (buf_) * BSZ + rb_ * 64); \
      gld16(Bb + (size_t)(rb_ + 8 + lrow) * KS + ko_, Bs + (buf_) * BSZ + (rb_ + 8) * 64); \
    } else { \
      const int rb_ = (half_) * 64 + w * 8; \
      gld16(Bb + (size_t)(rb_ + lrow) * KS + ko_,     Bs + (buf_) * BSZ + rb_ * 64); \
    } \
  } while (0)
#define MM(a_, x_, y_) a_ = __builtin_amdgcn_mfma_f32_16x16x32_bf16(x_, y_, a_, 0, 0, 0)
#define VM_STEADY() do { if (BN == 256) asm volatile("s_waitcnt vmcnt(4)" ::: "memory"); \
                         else           asm volatile("s_waitcnt vmcnt(2)" ::: "memory"); } while (0)

  // ---- prologue: K0 all halves -> buf0; K1 B halves -> buf1 (A halves follow in-loop)
  STG_A(0, 0, 0); STG_A(0, 1, 0);
  STG_B(0, 0, 0); STG_B(0, 1, 0);
  STG_B(1, 0, 1); STG_B(1, 1, 1);
  VM_STEADY();                                   // K0 landed; K1's B-halves in flight
  __builtin_amdgcn_s_barrier();

  for (int t = 0; t < NT; ++t) {
    const int buf = t & 1, nbuf = buf ^ 1;
    const int aB = buf * 16384, bB = buf * BSZ;
    short8 af[4][2], bqlo[NTH][2], bqhi[NTH][2];

    // ---------- phase 1: read A-lo + B-lo frags; stage A-lo(t+1) ----------
#pragma unroll
    for (int mt = 0; mt < 4; mt++) {
      af[mt][0] = *(const short8*)&As[aB + arow + mt * 1024 + co0];
      af[mt][1] = *(const short8*)&As[aB + arow + mt * 1024 + co1];
    }
#pragma unroll
    for (int nt = 0; nt < NTH; nt++) {
      bqlo[nt][0] = *(const short8*)&Bs[bB + brow + nt * 1024 + co0];
      bqlo[nt][1] = *(const short8*)&Bs[bB + brow + nt * 1024 + co1];
    }
    if (t + 1 < NT) STG_A(nbuf, 0, t + 1);
    __builtin_amdgcn_s_barrier();
    asm volatile("s_waitcnt lgkmcnt(0)" ::: "memory");
    __builtin_amdgcn_s_setprio(1);
#pragma unroll
    for (int mt = 0; mt < 4; mt++)
#pragma unroll
      for (int nt = 0; nt < NTH; nt++) {
        MM(acc[mt][nt], af[mt][0], bqlo[nt][0]);
        MM(acc[mt][nt], af[mt][1], bqlo[nt][1]);
      }
    __builtin_amdgcn_s_setprio(0);
    __builtin_amdgcn_s_barrier();

    // ---------- phase 2: read B-hi frags; stage A-hi(t+1) ----------
#pragma unroll
    for (int nt = 0; nt < NTH; nt++) {
      bqhi[nt][0] = *(const short8*)&Bs[bB + brow + (NTH + nt) * 1024 + co0];
      bqhi[nt][1] = *(const short8*)&Bs[bB + brow + (NTH + nt) * 1024 + co1];
    }
    if (t + 1 < NT) STG_A(nbuf, 1, t + 1);
    __builtin_amdgcn_s_barrier();
    asm volatile("s_waitcnt lgkmcnt(0)" ::: "memory");
    __builtin_amdgcn_s_setprio(1);
#pragma unroll
    for (int mt = 0; mt < 4; mt++)
#pragma unroll
      for (int nt = 0; nt < NTH; nt++) {
        MM(acc[mt][NTH + nt], af[mt][0], bqhi[nt][0]);
        MM(acc[mt][NTH + nt], af[mt][1], bqhi[nt][1]);
      }
    __builtin_amdgcn_s_setprio(0);
    __builtin_amdgcn_s_barrier();

    // ---------- phase 3: read A-hi frags (overwrite af); stage B-lo(t+2) ----------
#pragma unroll
    for (int mt = 0; mt < 4; mt++) {
      af[mt][0] = *(const short8*)&As[aB + arow + (4 + mt) * 1024 + co0];
      af[mt][1] = *(const short8*)&As[aB + arow + (4 + mt) * 1024 + co1];
    }
    if (t + 2 < NT) STG_B(buf, 0, t + 2);
    __builtin_amdgcn_s_barrier();
    asm volatile("s_waitcnt lgkmcnt(0)" ::: "memory");
    __builtin_amdgcn_s_setprio(1);
#pragma unroll
    for (int mt = 0; mt < 4; mt++)
#pragma unroll
      for (int nt = 0; nt < NTH; nt++) {
        MM(acc[4 + mt][NTH + nt], af[mt][0], bqhi[nt][0]);
        MM(acc[4 + mt][NTH + nt], af[mt][1], bqhi[nt][1]);
      }
    __builtin_amdgcn_s_setprio(0);
    __builtin_amdgcn_s_barrier();

    // ---------- phase 4: regs only (A-hi x B-lo); stage B-hi(t+2); counted vmcnt ----------
    if (t + 2 < NT) STG_B(buf, 1, t + 2);
    __builtin_amdgcn_s_barrier();
    __builtin_amdgcn_s_setprio(1);
#pragma unroll
    for (int mt = 0; mt < 4; mt++)
#pragma unroll
      for (int nt = 0; nt < NTH; nt++) {
        MM(acc[4 + mt][nt], af[mt][0], bqlo[nt][0]);
        MM(acc[4 + mt][nt], af[mt][1], bqlo[nt][1]);
      }
    __builtin_amdgcn_s_setprio(0);
    if (t + 2 < NT)      VM_STEADY();
    else if (t + 1 < NT) asm volatile("s_waitcnt vmcnt(0)" ::: "memory");
    __builtin_amdgcn_s_barrier();
  }
#undef STG_A
#undef STG_B
#undef MM
#undef VM_STEADY
}

// ---------------- GEMM1: h = relu(xb @ W1 + b1), bf16 out, 256x256 tile ----------------
// 1-D grid of 512 with XCD-aware decode: xcd = id&7 (dispatch round-robin) -> expert;
// all 16 n-blocks sharing an A-panel (and all m-blocks of that expert) run on ONE XCD,
// so xb-e + w1t-e panels are fetched into that XCD's L2 once instead of per-block.
__global__ __launch_bounds__(512, 2) void gemm_ffn1(
    const unsigned short* __restrict__ xb, const unsigned short* __restrict__ w1t,
    const float* __restrict__ b1, unsigned short* __restrict__ h,
    const int* __restrict__ counts)
{
  extern __shared__ unsigned short SMEM[];
  unsigned short* As = SMEM;              // 2 x 256 x 64 ushort = 64 KiB
  unsigned short* Bs = SMEM + 32768;      // 64 KiB
  const u32 id = blockIdx.x;              // 0..511
  const int e = id & 7;                   // = XCD for this block
  const int n0 = ((id >> 3) & 15) * 256;  // 16 n-blocks
  const int m0 = (id >> 7) * 256;         // 4 m-blocks
  int cnt = counts[e]; cnt = cnt < CAP ? cnt : CAP;
  if (m0 >= cnt) return;
  const unsigned short* Ab = xb + ((size_t)e * CAP + m0) * DDIM;
  const unsigned short* Bb = w1t + ((size_t)e * FDIM + n0) * DDIM;

  float4v acc[8][4] = {};
  gemm256_core<DDIM, 256>(Ab, Bb, As, Bs, 0, DDIM / 64, acc);

  const int tid = threadIdx.x;
  const int w = tid >> 6, lane = tid & 63;
  const int wr = w >> 2, wc = w & 3;
  const int l15 = lane & 15, quad = lane >> 4;
#pragma unroll
  for (int nt = 0; nt < 4; nt++) {
    const int col = n0 + wc * 64 + nt * 16 + l15;
    const float bias = b1[e * FDIM + col];
#pragma unroll
    for (int mt = 0; mt < 8; mt++) {
      const int rb = m0 + wr * 128 + mt * 16 + quad * 4;
#pragma unroll
      for (int r = 0; r < 4; r++) {
        float v = acc[mt][nt][r] + bias;
        v = v > 0.f ? v : 0.f;
        h[((size_t)e * CAP + rb + r) * FDIM + col] = f2bf(v);
      }
    }
  }
}

// ------- GEMM2: pt[kc] = h @ W2 (K-half), fp32 partials, 256x128 8-phase -------
// Split-K x2 with PLAIN STORES (no atomics -- round-2's pathology). Grid 512 1-D,
// active = 256 blocks = all CUs (round-5 counter: BM=256 full-K had only 128 active
// blocks -> half the GPU idle). kc in high bits keeps both K-halves of expert e on
// XCD e -> h/w2t panels stay L2-resident (round-4 win, FETCH 52 MiB).
__global__ __launch_bounds__(512, 2) void gemm_ffn2(
    const unsigned short* __restrict__ h, const unsigned short* __restrict__ w2t,
    float* __restrict__ pt, const int* __restrict__ counts)
{
  extern __shared__ unsigned short SMEM[];
  unsigned short* As = SMEM;              // 2 x 256 x 64 ushort = 64 KiB
  unsigned short* Bs = SMEM + 32768;      // 2 x 128 x 64 ushort = 32 KiB
  const u32 id = blockIdx.x;              // 0..511
  const int e = id & 7;                   // = XCD for this block
  const int n0 = ((id >> 3) & 7) * 128;   // 8 n-blocks
  const int m0 = ((id >> 6) & 3) * 256;   // 4 m-blocks
  const int kc = id >> 8;                 // 0..1 K-half
  int cnt = counts[e]; cnt = cnt < CAP ? cnt : CAP;
  if (m0 >= cnt) return;
  const unsigned short* Ab = h + ((size_t)e * CAP + m0) * FDIM;
  const unsigned short* Bb = w2t + ((size_t)e * DDIM + n0) * FDIM;

  float4v acc[8][2] = {};
  gemm256_core<FDIM, 128>(Ab, Bb, As, Bs, kc * (FDIM / 2), (FDIM / 2) / 64, acc);

  const int tid = threadIdx.x;
  const int w = tid >> 6, lane = tid & 63;
  const int wr = w >> 2, wc = w & 3;
  const int l15 = lane & 15, quad = lane >> 4;
  float* po = pt + (size_t)kc * (EXP * CAP) * DDIM + ((size_t)e * CAP + m0) * DDIM;
#pragma unroll
  for (int mt = 0; mt < 8; mt++) {
#pragma unroll
    for (int r = 0; r < 4; r++) {
      const int row = wr * 128 + mt * 16 + quad * 4 + r;
#pragma unroll
      for (int nt = 0; nt < 2; nt++) {
        const int col = n0 + wc * 32 + nt * 16 + l15;
        po[(size_t)row * DDIM + col] = acc[mt][nt][r];
      }
    }
  }
}

// ---------------- combine: y[t] = (pt0 + pt1 + b2) * gate, scatter fp32 ----------------
__global__ __launch_bounds__(256) void combine_kernel(
    const float* __restrict__ pt, const float* __restrict__ b2,
    const int* __restrict__ tlist, const float* __restrict__ gslot,
    const int* __restrict__ counts, float* __restrict__ y)
{
  const int wv = threadIdx.x >> 6, lane = threadIdx.x & 63;
  const int s = blockIdx.x * 4 + wv;       // slot id
  const int e = s >> 10, c = s & (CAP - 1);
  int cnt = counts[e]; cnt = cnt < CAP ? cnt : CAP;
  if (c >= cnt) return;
  const int t = tlist[s];
  const float g = gslot[s];
  const float* p0 = pt + (size_t)s * DDIM;
  const float* p1 = p0 + (size_t)(EXP * CAP) * DDIM;
  const float* br = b2 + e * DDIM;
  float* yr = y + (size_t)t * DDIM;
  const int c0 = lane * 16;
#pragma unroll
  for (int j = 0; j < 16; j += 4) {
    const float4 a = *(const float4*)&p0[c0 + j];
    const float4 b = *(const float4*)&p1[c0 + j];
    const float4 bb = *(const float4*)&br[c0 + j];
    float4 o;
    o.x = (a.x + b.x + bb.x) * g;
    o.y = (a.y + b.y + bb.y) * g;
    o.z = (a.z + b.z + bb.z) * g;
    o.w = (a.w + b.w + bb.w) * g;
    *(float4*)&yr[c0 + j] = o;
  }
}

extern "C" void kernel_launch(void* const* d_in, const int* in_sizes, int n_in,
                              void* d_out, int out_size, void* d_ws, size_t ws_size,
                              hipStream_t stream) {
  const float* x  = (const float*)d_in[0];
  const float* Wg = (const float*)d_in[1];
  const float* W1 = (const float*)d_in[2];
  const float* b1 = (const float*)d_in[3];
  const float* W2 = (const float*)d_in[4];
  const float* b2 = (const float*)d_in[5];
  float* out = (float*)d_out;
  char* ws = (char*)d_ws;

  int*            eidx  = (int*)(ws + O_EIDX);
  float*          gate  = (float*)(ws + O_GATE);
  int*            counts= (int*)(ws + O_COUNTS);
  float*          sump  = (float*)(ws + O_SUMP);
  float*          zsum  = (float*)(ws + O_ZSUM);
  int*            tlist = (int*)(ws + O_TLIST);
  float*          gslot = (float*)(ws + O_GSLOT);
  unsigned short* xb    = (unsigned short*)(ws + O_XB);
  unsigned short* wt    = (unsigned short*)(ws + O_WT);
  unsigned short* h     = (unsigned short*)(ws + O_H);
  float*          pt    = (float*)(ws + O_PT);

  // dynamic LDS for the 8-phase GEMMs (host-side attr, graph-capture safe)
  hipFuncSetAttribute((const void*)gemm_ffn1, hipFuncAttributeMaxDynamicSharedMemorySize, 131072);
  hipFuncSetAttribute((const void*)gemm_ffn2, hipFuncAttributeMaxDynamicSharedMemorySize, 98304);

  // zero y + scalar outputs (dropped tokens must stay 0), and the small accum region
  hipMemsetAsync(d_out, 0, (size_t)out_size * sizeof(float), stream);
  hipMemsetAsync(ws + O_COUNTS, 0, 256, stream);

  router_kernel<<<T_TOK / 4, 256, 0, stream>>>(x, Wg, eidx, gate, sump, zsum);
  scan_kernel<<<1, 512, 0, stream>>>(eidx, gate, tlist, gslot, counts, sump, zsum, out);
  dispatch_kernel<<<(EXP * CAP) / 4, 256, 0, stream>>>(x, tlist, counts, xb);

  // W1 [E][1024][4096] -> wt [E][4096][1024] bf16
  transpose_cvt<<<dim3(FDIM / 64, DDIM / 64, EXP), 256, 0, stream>>>(W1, wt, DDIM, FDIM);
  // XCD-swizzled 1-D grid: id&7 = expert = XCD
  gemm_ffn1<<<512, 512, 131072, stream>>>(xb, wt, b1, h, counts);

  // W2 [E][4096][1024] -> wt [E][1024][4096] bf16 (reuse buffer)
  transpose_cvt<<<dim3(DDIM / 64, FDIM / 64, EXP), 256, 0, stream>>>(W2, wt, FDIM, DDIM);
  // GEMM2: split-K x2 fp32 partials (plain stores), 256x128 8-phase, XCD-swizzled
  gemm_ffn2<<<512, 512, 98304, stream>>>(h, wt, pt, counts);
  // combine: sum partials + bias, gate, scatter to y
  combine_kernel<<<(EXP * CAP) / 4, 256, 0, stream>>>(pt, b2, tlist, gslot, counts, out);
}

// Round 7
// 503.339 us; speedup vs baseline: 1.0386x; 1.0386x over previous
//
#include <hip/hip_runtime.h>
#include <hip/hip_bf16.h>
#include <math.h>

// Problem constants (B=2,S=2048,D=1024,E=8,F=4096, capacity_factor=2.0)
#define T_TOK 4096
#define DDIM 1024
#define EXP 8
#define FDIM 4096
#define CAP 1024   // int(2.0 * 4096 / 8)

typedef __attribute__((ext_vector_type(8))) short short8;
typedef __attribute__((ext_vector_type(4))) float float4v;
typedef unsigned int u32;
typedef unsigned long long u64;

// ---- workspace layout (bytes) ----
#define O_EIDX   0            // int[4096]
#define O_GATE   (16<<10)     // float[4096]
#define O_COUNTS (32<<10)     // int[8]
#define O_TLIST  (40<<10)     // int[8*1024]
#define O_GSLOT  (72<<10)     // float[8*1024]
#define O_RSUM   (128<<10)    // float[1024][16] router per-block partials (64 KiB)
#define O_XB     (1<<20)      // bf16[8*1024*1024]   16 MiB
#define O_WT     (17<<20)     // bf16[8*4096*1024]   64 MiB  W1t
#define O_H      (81<<20)     // bf16[8*1024*4096]   64 MiB
#define O_WT2    (145<<20)    // bf16[8*1024*4096]   64 MiB  W2t

__device__ __forceinline__ unsigned short f2bf(float f) {
  __hip_bfloat16 b = __float2bfloat16(f);
  return *reinterpret_cast<unsigned short*>(&b);
}
__device__ __forceinline__ float bf2f(unsigned short u) {
  u32 x = ((u32)u) << 16;
  union { u32 u; float f; } c; c.u = x; return c.f;
}

__device__ __forceinline__ void gld16(const void* g, void* l) {
  __builtin_amdgcn_global_load_lds((const __attribute__((address_space(1))) u32*)g,
                                   (__attribute__((address_space(3))) u32*)l, 16, 0, 0);
}

// ---------------- router: logits (fp64 acc), softmax, argmax; NO global atomics ----------------
// Per-block loss partials go to rsum[block][0..8] (padded 64-B rows, plain stores);
// reduced in scan_kernel. (Round-6 suspicion: 9216 device atomicAdds on 1-2 cache
// lines serialize at the L2 atomic unit.)
__global__ __launch_bounds__(256) void router_kernel(
    const float* __restrict__ x, const float* __restrict__ wg,
    int* __restrict__ eidx, float* __restrict__ gate,
    float* __restrict__ rsum)
{
  __shared__ float bp[9];
  const int tid = threadIdx.x;
  if (tid < 9) bp[tid] = 0.0f;
  __syncthreads();
  const int wv = tid >> 6, lane = tid & 63;
  const int t = blockIdx.x * 4 + wv;
  const float* xr = x + (size_t)t * DDIM;
  double acc[8] = {0,0,0,0,0,0,0,0};
#pragma unroll
  for (int j = 0; j < 4; j++) {
    const int d0 = j * 256 + lane * 4;
    const float4 xv = *(const float4*)&xr[d0];
    const float xd[4] = {xv.x, xv.y, xv.z, xv.w};
#pragma unroll
    for (int u = 0; u < 4; u++) {
      const float* wr = wg + (size_t)(d0 + u) * 8;
      const float4 w0 = *(const float4*)wr;
      const float4 w1 = *(const float4*)(wr + 4);
      const double xdd = (double)xd[u];
      acc[0] += xdd * (double)w0.x; acc[1] += xdd * (double)w0.y;
      acc[2] += xdd * (double)w0.z; acc[3] += xdd * (double)w0.w;
      acc[4] += xdd * (double)w1.x; acc[5] += xdd * (double)w1.y;
      acc[6] += xdd * (double)w1.z; acc[7] += xdd * (double)w1.w;
    }
  }
#pragma unroll
  for (int e = 0; e < 8; e++)
#pragma unroll
    for (int off = 32; off; off >>= 1)
      acc[e] += __shfl_xor(acc[e], off);
  if (lane == 0) {
    double m = acc[0]; int am = 0;
#pragma unroll
    for (int e = 1; e < 8; e++) if (acc[e] > m) { m = acc[e]; am = e; }
    float p[8]; float se = 0.f;
#pragma unroll
    for (int e = 0; e < 8; e++) { p[e] = __expf((float)(acc[e] - m)); se += p[e]; }
    const float inv = 1.f / se;
#pragma unroll
    for (int e = 0; e < 8; e++) atomicAdd(&bp[e], p[e] * inv);   // LDS atomics (block-local)
    const float z = logf(se) + (float)m;
    atomicAdd(&bp[8], z * z);
    eidx[t] = am;
    gate[t] = p[am] * inv;
  }
  __syncthreads();
  if (tid < 9) rsum[(blockIdx.x << 4) + tid] = bp[tid];
}

// ------- scan: per-expert positions (token order) + rsum reduction + loss finalize -------
__global__ __launch_bounds__(512) void scan_kernel(
    const int* __restrict__ eidx, const float* __restrict__ gate,
    int* __restrict__ tlist, float* __restrict__ gslot, int* __restrict__ counts,
    const float* __restrict__ rsum, float* __restrict__ y)
{
  __shared__ int se[T_TOK];
  __shared__ int cshare[8];
  __shared__ float red[512][10];
  const int tid = threadIdx.x;
  for (int i = tid; i < T_TOK; i += 512) se[i] = eidx[i];
  __syncthreads();
  const int w = tid >> 6, lane = tid & 63;
  int base = 0;
  for (int ch = 0; ch < T_TOK / 64; ch++) {
    const int t = ch * 64 + lane;
    const int e = se[t];
    const u64 m = __ballot(e == w);
    if (e == w) {
      const int p = base + __popcll(m & ((1ull << lane) - 1ull));
      if (p < CAP) {
        tlist[w * CAP + p] = t;
        gslot[w * CAP + p] = gate[t];
      }
    }
    base += __popcll(m);
  }
  if (lane == 0) { counts[w] = base; cshare[w] = base; }  // raw count (aux loss)

  // ---- reduce router partials: 1024 blocks x 9 counters ----
  float f[9];
#pragma unroll
  for (int c = 0; c < 9; c++) f[c] = 0.f;
  for (int b = tid; b < 1024; b += 512) {
    const float* rr = &rsum[b << 4];
#pragma unroll
    for (int c = 0; c < 9; c++) f[c] += rr[c];
  }
#pragma unroll
  for (int c = 0; c < 9; c++) red[tid][c] = f[c];
  __syncthreads();
  for (int s = 256; s > 0; s >>= 1) {
    if (tid < s)
#pragma unroll
      for (int c = 0; c < 9; c++) red[tid][c] += red[tid + s][c];
    __syncthreads();
  }
  if (tid == 0) {
    float aux = 0.f;
#pragma unroll
    for (int e = 0; e < 8; e++) aux += (float)cshare[e] * red[0][e];
    float* outs = y + (size_t)T_TOK * DDIM;
    outs[0] = 8.f * aux / ((float)T_TOK * (float)T_TOK);
    outs[1] = red[0][8] * (1.f / (float)T_TOK);
  }
}

// ---------------- dispatch: gather kept tokens into compact bf16 buffer ----------------
__global__ __launch_bounds__(256) void dispatch_kernel(
    const float* __restrict__ x, const int* __restrict__ tlist,
    const int* __restrict__ counts, unsigned short* __restrict__ xb)
{
  const int wv = threadIdx.x >> 6, lane = threadIdx.x & 63;
  const int s = blockIdx.x * 4 + wv;           // slot id
  const int e = s >> 10, c = s & (CAP - 1);
  int cnt = counts[e]; cnt = cnt < CAP ? cnt : CAP;
  if (c >= cnt) return;
  const int t = tlist[s];
  const float* xr = x + (size_t)t * DDIM;
  unsigned short* orow = xb + (size_t)s * DDIM;
#pragma unroll
  for (int j = 0; j < 4; j++) {
    const int d0 = j * 256 + lane * 4;
    const float4 v = *(const float4*)&xr[d0];
    const u64 pk = (u64)f2bf(v.x) | ((u64)f2bf(v.y) << 16) |
                   ((u64)f2bf(v.z) << 32) | ((u64)f2bf(v.w) << 48);
    *(u64*)&orow[d0] = pk;
  }
}

// -------- merged transpose + fp32->bf16 for BOTH weights (one launch) --------
// z<8: W1 expert z, [R=1024][C=4096] -> wt1 [C][R]; z>=8: W2 expert z-8,
// [R=4096][C=1024] -> wt2 [C][R]. Same 64x64 tile kernel, decode per z.
__global__ __launch_bounds__(256) void transpose_both(
    const float* __restrict__ W1, const float* __restrict__ W2,
    unsigned short* __restrict__ wt1, unsigned short* __restrict__ wt2)
{
  __shared__ float tile[64][65];
  const int z = blockIdx.z;
  const int isW2 = z >> 3;
  const int e = z & 7;
  const int R = isW2 ? FDIM : DDIM;
  const int C = isW2 ? DDIM : FDIM;
  const float* src = (isW2 ? W2 : W1) + (size_t)e * R * C;
  unsigned short* dst = (isW2 ? wt2 : wt1) + (size_t)e * R * C;
  const u32 bx = blockIdx.x;                  // 0..1023
  const int cx = isW2 ? (bx & 15) : (bx & 63);
  const int cy = isW2 ? (bx >> 4) : (bx >> 6);
  const int r0 = cy * 64, c0 = cx * 64;
  const int t = threadIdx.x;
  const int lr = t >> 4, lc = (t & 15) * 4;
#pragma unroll
  for (int p = 0; p < 4; p++) {
    const float4 v = *(const float4*)&src[(size_t)(r0 + p * 16 + lr) * C + c0 + lc];
    tile[p * 16 + lr][lc + 0] = v.x; tile[p * 16 + lr][lc + 1] = v.y;
    tile[p * 16 + lr][lc + 2] = v.z; tile[p * 16 + lr][lc + 3] = v.w;
  }
  __syncthreads();
  const int n = t >> 2;            // out row within tile (0..63)
  const int k0 = (t & 3) * 16;
  unsigned short o[16];
#pragma unroll
  for (int j = 0; j < 16; j++) o[j] = f2bf(tile[k0 + j][n]);
  unsigned short* d = &dst[(size_t)(c0 + n) * R + r0 + k0];
  *(short8*)d = *(short8*)&o[0];
  *(short8*)(d + 8) = *(short8*)&o[8];
}

// ======================= GEMM core: 256xBN, BK=64, 4-phase counted-vmcnt schedule =========
// LDS swizzle: chunk c (8 ushorts) of row r holds global k-chunk c ^ (r&7) (conflict-free).
// Staging source offset per lane: ((lane&7) ^ (lane>>3)) * 8; frag chunk: (ks*4+quad)^(l15&7).
// 8 waves (2M x BN/64-wide n each), 512 threads. Per K-tile: 4 phases
// {ds_read quadrant ∥ stage 1 half-tile; barrier; lgkmcnt(0); setprio(1); MFMA; setprio(0);
// barrier}; staging spiral A-lo(t+1), A-hi(t+1), B-lo(t+2), B-hi(t+2); one counted vmcnt
// per K-tile, never 0 mid-loop.
template<int KS, int BN>
__device__ __forceinline__ void gemm256_core(
    const unsigned short* __restrict__ Ab, const unsigned short* __restrict__ Bb,
    unsigned short* As, unsigned short* Bs,
    int k_lo, int NT, float4v (*acc)[BN / 64])
{
  const int NTH = BN / 128;       // n-frags per lo/hi quadrant per wave (2 or 1)
  const int BSZ = BN * 64;        // B buffer elems per K-tile
  const int tid = threadIdx.x;
  const int w = tid >> 6, lane = tid & 63;
  const int lrow = lane >> 3;                 // 0..7
  const int lk_sw = ((lane & 7) ^ lrow) * 8;  // swizzled source k-offset (elements)
  const int wr = w >> 2, wc = w & 3;
  const int l15 = lane & 15, quad = lane >> 4;
  const int xq = l15 & 7;
  const int co0 = (quad ^ xq) * 8;            // frag chunk offset, ks=0
  const int co1 = ((4 + quad) ^ xq) * 8;      // frag chunk offset, ks=1
  const int arow = (wr * 128 + l15) * 64;     // A frag row base (elements)
  const int brow = (wc * (BN / 4) + l15) * 64;// B frag row base (elements)

#define STG_A(buf_, half_, tk_) do { \
    const int rb_ = (half_) * 128 + w * 16; \
    const size_t ko_ = (size_t)(k_lo + ((tk_) << 6) + lk_sw); \
    gld16(Ab + (size_t)(rb_ + lrow) * KS + ko_,     As + (buf_) * 16384 + rb_ * 64); \
    gld16(Ab + (size_t)(rb_ + 8 + lrow) * KS + ko_, As + (buf_) * 16384 + (rb_ + 8) * 64); \
  } while (0)
#define STG_B(buf_, half_, tk_) do { \
    const size_t ko_ = (size_t)(k_lo + ((tk_) << 6) + lk_sw); \
    if (BN == 256) { \
      const int rb_ = (half_) * 128 + w * 16; \
      gld16(Bb + (size_t)(rb_ + lrow) * KS + ko_,     Bs + (buf_) * BSZ + rb_ * 64); \
      gld16(Bb + (size_t)(rb_ + 8 + lrow) * KS + ko_, Bs + (buf_) * BSZ + (rb_ + 8) * 64); \
    } else { \
      const int rb_ = (half_) * 64 + w * 8; \
      gld16(Bb + (size_t)(rb_ + lrow) * KS + ko_,     Bs + (buf_) * BSZ + rb_ * 64); \
    } \
  } while (0)
#define MM(a_, x_, y_) a_ = __builtin_amdgcn_mfma_f32_16x16x32_bf16(x_, y_, a_, 0, 0, 0)
#define VM_STEADY() do { if (BN == 256) asm volatile("s_waitcnt vmcnt(4)" ::: "memory"); \
                         else           asm volatile("s_waitcnt vmcnt(2)" ::: "memory"); } while (0)

  // ---- prologue: K0 all halves -> buf0; K1 B halves -> buf1 (A halves follow in-loop)
  STG_A(0, 0, 0); STG_A(0, 1, 0);
  STG_B(0, 0, 0); STG_B(0, 1, 0);
  STG_B(1, 0, 1); STG_B(1, 1, 1);
  VM_STEADY();                                   // K0 landed; K1's B-halves in flight
  __builtin_amdgcn_s_barrier();

  for (int t = 0; t < NT; ++t) {
    const int buf = t & 1, nbuf = buf ^ 1;
    const int aB = buf * 16384, bB = buf * BSZ;
    short8 af[4][2], bqlo[NTH][2], bqhi[NTH][2];

    // ---------- phase 1: read A-lo + B-lo frags; stage A-lo(t+1) ----------
#pragma unroll
    for (int mt = 0; mt < 4; mt++) {
      af[mt][0] = *(const short8*)&As[aB + arow + mt * 1024 + co0];
      af[mt][1] = *(const short8*)&As[aB + arow + mt * 1024 + co1];
    }
#pragma unroll
    for (int nt = 0; nt < NTH; nt++) {
      bqlo[nt][0] = *(const short8*)&Bs[bB + brow + nt * 1024 + co0];
      bqlo[nt][1] = *(const short8*)&Bs[bB + brow + nt * 1024 + co1];
    }
    if (t + 1 < NT) STG_A(nbuf, 0, t + 1);
    __builtin_amdgcn_s_barrier();
    asm volatile("s_waitcnt lgkmcnt(0)" ::: "memory");
    __builtin_amdgcn_s_setprio(1);
#pragma unroll
    for (int mt = 0; mt < 4; mt++)
#pragma unroll
      for (int nt = 0; nt < NTH; nt++) {
        MM(acc[mt][nt], af[mt][0], bqlo[nt][0]);
        MM(acc[mt][nt], af[mt][1], bqlo[nt][1]);
      }
    __builtin_amdgcn_s_setprio(0);
    __builtin_amdgcn_s_barrier();

    // ---------- phase 2: read B-hi frags; stage A-hi(t+1) ----------
#pragma unroll
    for (int nt = 0; nt < NTH; nt++) {
      bqhi[nt][0] = *(const short8*)&Bs[bB + brow + (NTH + nt) * 1024 + co0];
      bqhi[nt][1] = *(const short8*)&Bs[bB + brow + (NTH + nt) * 1024 + co1];
    }
    if (t + 1 < NT) STG_A(nbuf, 1, t + 1);
    __builtin_amdgcn_s_barrier();
    asm volatile("s_waitcnt lgkmcnt(0)" ::: "memory");
    __builtin_amdgcn_s_setprio(1);
#pragma unroll
    for (int mt = 0; mt < 4; mt++)
#pragma unroll
      for (int nt = 0; nt < NTH; nt++) {
        MM(acc[mt][NTH + nt], af[mt][0], bqhi[nt][0]);
        MM(acc[mt][NTH + nt], af[mt][1], bqhi[nt][1]);
      }
    __builtin_amdgcn_s_setprio(0);
    __builtin_amdgcn_s_barrier();

    // ---------- phase 3: read A-hi frags (overwrite af); stage B-lo(t+2) ----------
#pragma unroll
    for (int mt = 0; mt < 4; mt++) {
      af[mt][0] = *(const short8*)&As[aB + arow + (4 + mt) * 1024 + co0];
      af[mt][1] = *(const short8*)&As[aB + arow + (4 + mt) * 1024 + co1];
    }
    if (t + 2 < NT) STG_B(buf, 0, t + 2);
    __builtin_amdgcn_s_barrier();
    asm volatile("s_waitcnt lgkmcnt(0)" ::: "memory");
    __builtin_amdgcn_s_setprio(1);
#pragma unroll
    for (int mt = 0; mt < 4; mt++)
#pragma unroll
      for (int nt = 0; nt < NTH; nt++) {
        MM(acc[4 + mt][NTH + nt], af[mt][0], bqhi[nt][0]);
        MM(acc[4 + mt][NTH + nt], af[mt][1], bqhi[nt][1]);
      }
    __builtin_amdgcn_s_setprio(0);
    __builtin_amdgcn_s_barrier();

    // ---------- phase 4: regs only (A-hi x B-lo); stage B-hi(t+2); counted vmcnt ----------
    if (t + 2 < NT) STG_B(buf, 1, t + 2);
    __builtin_amdgcn_s_barrier();
    __builtin_amdgcn_s_setprio(1);
#pragma unroll
    for (int mt = 0; mt < 4; mt++)
#pragma unroll
      for (int nt = 0; nt < NTH; nt++) {
        MM(acc[4 + mt][nt], af[mt][0], bqlo[nt][0]);
        MM(acc[4 + mt][nt], af[mt][1], bqlo[nt][1]);
      }
    __builtin_amdgcn_s_setprio(0);
    if (t + 2 < NT)      VM_STEADY();
    else if (t + 1 < NT) asm volatile("s_waitcnt vmcnt(0)" ::: "memory");
    __builtin_amdgcn_s_barrier();
  }
#undef STG_A
#undef STG_B
#undef MM
#undef VM_STEADY
}

// ---------------- GEMM1: h = relu(xb @ W1 + b1), bf16 out, 256x256 tile ----------------
// 1-D grid of 512 with XCD-aware decode: xcd = id&7 (dispatch round-robin) -> expert;
// all n-blocks sharing an A-panel run on ONE XCD -> panels L2-resident (round-4 win).
__global__ __launch_bounds__(512, 2) void gemm_ffn1(
    const unsigned short* __restrict__ xb, const unsigned short* __restrict__ w1t,
    const float* __restrict__ b1, unsigned short* __restrict__ h,
    const int* __restrict__ counts)
{
  extern __shared__ unsigned short SMEM[];
  unsigned short* As = SMEM;              // 2 x 256 x 64 ushort = 64 KiB
  unsigned short* Bs = SMEM + 32768;      // 64 KiB
  const u32 id = blockIdx.x;              // 0..511
  const int e = id & 7;                   // = XCD for this block
  const int n0 = ((id >> 3) & 15) * 256;  // 16 n-blocks
  const int m0 = (id >> 7) * 256;         // 4 m-blocks
  int cnt = counts[e]; cnt = cnt < CAP ? cnt : CAP;
  if (m0 >= cnt) return;
  const unsigned short* Ab = xb + ((size_t)e * CAP + m0) * DDIM;
  const unsigned short* Bb = w1t + ((size_t)e * FDIM + n0) * DDIM;

  float4v acc[8][4] = {};
  gemm256_core<DDIM, 256>(Ab, Bb, As, Bs, 0, DDIM / 64, acc);

  const int tid = threadIdx.x;
  const int w = tid >> 6, lane = tid & 63;
  const int wr = w >> 2, wc = w & 3;
  const int l15 = lane & 15, quad = lane >> 4;
#pragma unroll
  for (int nt = 0; nt < 4; nt++) {
    const int col = n0 + wc * 64 + nt * 16 + l15;
    const float bias = b1[e * FDIM + col];
#pragma unroll
    for (int mt = 0; mt < 8; mt++) {
      const int rb = m0 + wr * 128 + mt * 16 + quad * 4;
#pragma unroll
      for (int r = 0; r < 4; r++) {
        float v = acc[mt][nt][r] + bias;
        v = v > 0.f ? v : 0.f;
        h[((size_t)e * CAP + rb + r) * FDIM + col] = f2bf(v);
      }
    }
  }
}

// ------- GEMM2 + fused combine: y[t] = (h @ W2 + b2) * gate, 256x128 8-phase -------
// Round-5 version (best total 514.6): full-K per block, no partials, no atomics;
// gated fp32 scatter via tlist; rows >= cnt skipped (y stays 0 from memset).
__global__ __launch_bounds__(512, 2) void gemm_ffn2(
    const unsigned short* __restrict__ h, const unsigned short* __restrict__ w2t,
    const float* __restrict__ b2, const int* __restrict__ tlist,
    const float* __restrict__ gslot, const int* __restrict__ counts,
    float* __restrict__ y)
{
  extern __shared__ unsigned short SMEM[];
  unsigned short* As = SMEM;              // 2 x 256 x 64 ushort = 64 KiB
  unsigned short* Bs = SMEM + 32768;      // 2 x 128 x 64 ushort = 32 KiB
  const u32 id = blockIdx.x;              // 0..255
  const int e = id & 7;                   // = XCD for this block
  const int n0 = ((id >> 3) & 7) * 128;   // 8 n-blocks
  const int m0 = (id >> 6) * 256;         // 4 m-blocks
  int cnt = counts[e]; cnt = cnt < CAP ? cnt : CAP;
  if (m0 >= cnt) return;
  const unsigned short* Ab = h + ((size_t)e * CAP + m0) * FDIM;
  const unsigned short* Bb = w2t + ((size_t)e * DDIM + n0) * FDIM;

  float4v acc[8][2] = {};
  gemm256_core<FDIM, 128>(Ab, Bb, As, Bs, 0, FDIM / 64, acc);

  const int tid = threadIdx.x;
  const int w = tid >> 6, lane = tid & 63;
  const int wr = w >> 2, wc = w & 3;
  const int l15 = lane & 15, quad = lane >> 4;
#pragma unroll
  for (int mt = 0; mt < 8; mt++) {
#pragma unroll
    for (int r = 0; r < 4; r++) {
      const int srow = m0 + wr * 128 + mt * 16 + quad * 4 + r;
      if (srow < cnt) {
        const int slot = e * CAP + srow;
        const int t = tlist[slot];
        const float g = gslot[slot];
        float* yr = y + (size_t)t * DDIM;
#pragma unroll
        for (int nt = 0; nt < 2; nt++) {
          const int col = n0 + wc * 32 + nt * 16 + l15;
          yr[col] = (acc[mt][nt][r] + b2[e * DDIM + col]) * g;
        }
      }
    }
  }
}

extern "C" void kernel_launch(void* const* d_in, const int* in_sizes, int n_in,
                              void* d_out, int out_size, void* d_ws, size_t ws_size,
                              hipStream_t stream) {
  const float* x  = (const float*)d_in[0];
  const float* Wg = (const float*)d_in[1];
  const float* W1 = (const float*)d_in[2];
  const float* b1 = (const float*)d_in[3];
  const float* W2 = (const float*)d_in[4];
  const float* b2 = (const float*)d_in[5];
  float* out = (float*)d_out;
  char* ws = (char*)d_ws;

  int*            eidx  = (int*)(ws + O_EIDX);
  float*          gate  = (float*)(ws + O_GATE);
  int*            counts= (int*)(ws + O_COUNTS);
  int*            tlist = (int*)(ws + O_TLIST);
  float*          gslot = (float*)(ws + O_GSLOT);
  float*          rsum  = (float*)(ws + O_RSUM);
  unsigned short* xb    = (unsigned short*)(ws + O_XB);
  unsigned short* wt1   = (unsigned short*)(ws + O_WT);
  unsigned short* h     = (unsigned short*)(ws + O_H);
  unsigned short* wt2   = (unsigned short*)(ws + O_WT2);

  // dynamic LDS for the 8-phase GEMMs (host-side attr, graph-capture safe)
  hipFuncSetAttribute((const void*)gemm_ffn1, hipFuncAttributeMaxDynamicSharedMemorySize, 131072);
  hipFuncSetAttribute((const void*)gemm_ffn2, hipFuncAttributeMaxDynamicSharedMemorySize, 98304);

  // zero y + scalar outputs (dropped tokens must stay 0)
  hipMemsetAsync(d_out, 0, (size_t)out_size * sizeof(float), stream);

  router_kernel<<<T_TOK / 4, 256, 0, stream>>>(x, Wg, eidx, gate, rsum);
  scan_kernel<<<1, 512, 0, stream>>>(eidx, gate, tlist, gslot, counts, rsum, out);
  dispatch_kernel<<<(EXP * CAP) / 4, 256, 0, stream>>>(x, tlist, counts, xb);

  // both weight transposes in ONE launch: W1 -> wt1, W2 -> wt2
  transpose_both<<<dim3(1024, 1, 16), 256, 0, stream>>>(W1, W2, wt1, wt2);

  // XCD-swizzled 1-D grids: id&7 = expert = XCD
  gemm_ffn1<<<512, 512, 131072, stream>>>(xb, wt1, b1, h, counts);
  gemm_ffn2<<<256, 512, 98304, stream>>>(h, wt2, b2, tlist, gslot, counts, out);
}